// Round 1
// baseline (2268.783 us; speedup 1.0000x reference)
//
#include <hip/hip_runtime.h>
#include <hip/hip_bf16.h>
#include <stdint.h>

// Problem constants (fixed by reference)
#define NB 256      // batch
#define NT 1024     // timesteps
#define NF 128      // features
#define NU 64       // units

typedef __attribute__((ext_vector_type(8))) short bf16x8;
typedef __attribute__((ext_vector_type(4))) float f32x4;
typedef __attribute__((ext_vector_type(4))) unsigned short u16x4;

static __device__ __forceinline__ unsigned short f2bf(float f) {
  unsigned int u = __builtin_bit_cast(unsigned int, f);
  unsigned int r = (u + 0x7fffu + ((u >> 16) & 1u)) >> 16;   // RNE
  return (unsigned short)r;
}
static __device__ __forceinline__ float bf2f(unsigned short h) {
  unsigned int u = ((unsigned int)h) << 16;
  return __builtin_bit_cast(float, u);
}
static __device__ __forceinline__ f32x4 mfma16(bf16x8 a, bf16x8 b, f32x4 c) {
  return __builtin_amdgcn_mfma_f32_16x16x32_bf16(a, b, c, 0, 0, 0);
}

// ---------------- ws layout (float units unless noted) ----------------
// W1   : 64 x 704 fp32 at [0, 45056)          cols: S|SPm|SPl|SEm|SEl|SGr(192)|SEG(192)
// WX   : 128 x 320 fp32 at [45056, 86016)     cols: Wqmu|Wqlv|Wg2(192)
// tmpGx: 128 x 192 fp32 at [86016, 110592)
// WXfrag: 40960 bf16 (u16) at float-offset 110592
// afrag : [t][bb(16)][ct(20)][lane(64)][j(4)] bf16 at byte offset 1<<20 (160 MB)

// =============== fold 1: first-level weight products ===============
__global__ __launch_bounds__(256) void k_fold1(
    const float* __restrict__ Win, const float* __restrict__ S,
    const float* __restrict__ Emu, const float* __restrict__ Elv,
    const float* __restrict__ Pm, const float* __restrict__ Pl,
    const float* __restrict__ G, const float* __restrict__ Gr,
    float* __restrict__ W1, float* __restrict__ WX, float* __restrict__ tmpGx) {
  int id = blockIdx.x * 256 + threadIdx.x;
  if (id < 8192) {                       // Wqmu = Win @ Emu[:128]
    int f = id >> 6, u = id & 63;
    float s = 0.f;
    for (int k = 0; k < 128; ++k) s += Win[f * 128 + k] * Emu[k * 64 + u];
    WX[f * 320 + u] = s;
  } else if (id < 16384) {               // Wqlv = Win @ Elv[:128]
    int r = id - 8192; int f = r >> 6, u = r & 63;
    float s = 0.f;
    for (int k = 0; k < 128; ++k) s += Win[f * 128 + k] * Elv[k * 64 + u];
    WX[f * 320 + 64 + u] = s;
  } else if (id < 40960) {               // tmpGx = Win @ G[:128]
    int r = id - 16384; int f = r / 192, n = r % 192;
    float s = 0.f;
    for (int k = 0; k < 128; ++k) s += Win[f * 128 + k] * G[k * 192 + n];
    tmpGx[f * 192 + n] = s;
  } else if (id < 45056) {               // S copy
    int r = id - 40960; int i = r >> 6, u = r & 63;
    W1[i * 704 + u] = S[i * 64 + u];
  } else if (id < 49152) {               // SPm = S @ Pm
    int r = id - 45056; int i = r >> 6, u = r & 63;
    float s = 0.f;
    for (int k = 0; k < 64; ++k) s += S[i * 64 + k] * Pm[k * 64 + u];
    W1[i * 704 + 64 + u] = s;
  } else if (id < 53248) {               // SPl = S @ Pl
    int r = id - 49152; int i = r >> 6, u = r & 63;
    float s = 0.f;
    for (int k = 0; k < 64; ++k) s += S[i * 64 + k] * Pl[k * 64 + u];
    W1[i * 704 + 128 + u] = s;
  } else if (id < 57344) {               // SEm = S @ Emu[128:]
    int r = id - 53248; int i = r >> 6, u = r & 63;
    float s = 0.f;
    for (int k = 0; k < 64; ++k) s += S[i * 64 + k] * Emu[(128 + k) * 64 + u];
    W1[i * 704 + 192 + u] = s;
  } else if (id < 61440) {               // SEl = S @ Elv[128:]
    int r = id - 57344; int i = r >> 6, u = r & 63;
    float s = 0.f;
    for (int k = 0; k < 64; ++k) s += S[i * 64 + k] * Elv[(128 + k) * 64 + u];
    W1[i * 704 + 256 + u] = s;
  } else if (id < 73728) {               // SGr = S @ Gr
    int r = id - 61440; int i = r / 192, n = r % 192;
    float s = 0.f;
    for (int k = 0; k < 64; ++k) s += S[i * 64 + k] * Gr[k * 192 + n];
    W1[i * 704 + 320 + n] = s;
  }
}

// =============== fold 2: second-level products (need fold1) ===============
__global__ __launch_bounds__(256) void k_fold2(
    const float* __restrict__ G, float* __restrict__ W1,
    float* __restrict__ WX, const float* __restrict__ tmpGx) {
  int id = blockIdx.x * 256 + threadIdx.x;
  if (id < 24576) {                      // Wg2 = tmpGx + Wqmu @ Gz
    int f = id / 192, n = id % 192;
    float s = tmpGx[f * 192 + n];
    for (int u = 0; u < 64; ++u) s += WX[f * 320 + u] * G[(128 + u) * 192 + n];
    WX[f * 320 + 128 + n] = s;
  } else if (id < 36864) {               // SEG = SEm @ Gz
    int r = id - 24576; int i = r / 192, n = r % 192;
    float s = 0.f;
    for (int u = 0; u < 64; ++u) s += W1[i * 704 + 192 + u] * G[(128 + u) * 192 + n];
    W1[i * 704 + 512 + n] = s;
  }
}

// =============== fold 3: pack WX into MFMA B-fragment order (bf16) ===============
__global__ __launch_bounds__(256) void k_fold3(
    const float* __restrict__ WX, unsigned short* __restrict__ WXfrag) {
  int d = blockIdx.x * 256 + threadIdx.x;   // 40960 elements
  if (d < 40960) {
    int i = d & 7, lane = (d >> 3) & 63, ks = (d >> 9) & 3, ct = d >> 11;
    int k = ks * 32 + (lane >> 4) * 8 + i;
    int n = ct * 16 + (lane & 15);
    WXfrag[d] = f2bf(WX[k * 320 + n]);
  }
}

// =============== projection GEMM: a = x @ WX, output in consumer-fragment order ===============
// grid 2048: wg -> t = wg>>1, b0 = (wg&1)*128. 512 threads = 8 waves.
__global__ __launch_bounds__(512, 1) void k_proj(
    const float* __restrict__ x, const unsigned short* __restrict__ WXfrag,
    unsigned short* __restrict__ afrag) {
  extern __shared__ char smem[];
  unsigned short* A  = (unsigned short*)smem;          // 128x128 bf16, XOR-swizzled (32 KB)
  unsigned short* Bf = (unsigned short*)(smem + 32768);// fragment-packed WX (80 KB)
  const int wgid = blockIdx.x;
  const int t = wgid >> 1, b0 = (wgid & 1) << 7;
  const int tid = threadIdx.x;

  // --- B staging: linear 80 KB copy (global -> LDS) ---
  {
    const f32x4* src = (const f32x4*)WXfrag;  // 5120 x 16B
    f32x4* dst = (f32x4*)Bf;
#pragma unroll
    for (int j = 0; j < 10; ++j) {
      int o = tid + j * 512;
      dst[o] = src[o];
    }
  }
  // --- A staging: x rows (b0..b0+127) at fixed t, cvt fp32->bf16, swizzled ---
  {
    int row = tid >> 2, fq = tid & 3;
    const float* xs = x + ((size_t)(b0 + row) * NT + t) * NF + fq * 32;
#pragma unroll
    for (int i = 0; i < 4; ++i) {
      f32x4 v0 = *(const f32x4*)(xs + i * 8);
      f32x4 v1 = *(const f32x4*)(xs + i * 8 + 4);
      bf16x8 p;
#pragma unroll
      for (int e = 0; e < 4; ++e) { p[e] = (short)f2bf(v0[e]); p[4 + e] = (short)f2bf(v1[e]); }
      int byte = (row * 256 + fq * 64 + i * 16) ^ ((row & 7) << 4);
      *(bf16x8*)((char*)A + byte) = p;
    }
  }
  __syncthreads();

  const int wv = tid >> 6, ln = tid & 63;
  const int mh = wv >> 2, ng = wv & 3;      // m-half (64 rows), n-group (5 ct)
  const int m15 = ln & 15, kq = ln >> 4;

  bf16x8 af[4][4];
#pragma unroll
  for (int mt = 0; mt < 4; ++mt) {
    int row = mh * 64 + mt * 16 + m15;
#pragma unroll
    for (int ks = 0; ks < 4; ++ks) {
      int byte = (row * 256 + ks * 64 + kq * 16) ^ ((row & 7) << 4);
      af[mt][ks] = *(const bf16x8*)((const char*)A + byte);
    }
  }
  f32x4 acc[5][4];
#pragma unroll
  for (int c5 = 0; c5 < 5; ++c5)
#pragma unroll
    for (int mt = 0; mt < 4; ++mt) acc[c5][mt] = (f32x4){0.f, 0.f, 0.f, 0.f};

#pragma unroll
  for (int c5 = 0; c5 < 5; ++c5) {
    int ct = ng * 5 + c5;
    bf16x8 bfr[4];
#pragma unroll
    for (int ks = 0; ks < 4; ++ks)
      bfr[ks] = *(const bf16x8*)((const char*)Bf + ((size_t)((ct * 4 + ks) * 64 + ln)) * 16);
#pragma unroll
    for (int mt = 0; mt < 4; ++mt)
#pragma unroll
      for (int ks = 0; ks < 4; ++ks)
        acc[c5][mt] = mfma16(af[mt][ks], bfr[ks], acc[c5][mt]);
  }
  // --- epilogue: store in consumer-fragment order, 8B per lane ---
#pragma unroll
  for (int c5 = 0; c5 < 5; ++c5) {
    int ct = ng * 5 + c5;
#pragma unroll
    for (int mt = 0; mt < 4; ++mt) {
      int bb = (b0 >> 4) + mh * 4 + mt;
      size_t idx = (((size_t)t * 16 + bb) * 20 + ct) * 64 + ln;
      u16x4 pk;
#pragma unroll
      for (int j = 0; j < 4; ++j) pk[j] = f2bf(acc[c5][mt][j]);
      *(u16x4*)(afrag + idx * 4) = pk;
    }
  }
}

// =============== the scan: 16 wgs x 16 rows, 4 waves, weights in registers ===============
__global__ __launch_bounds__(256, 1) void k_scan(
    const float* __restrict__ W1, const unsigned short* __restrict__ afrag,
    const float* __restrict__ G, const float* __restrict__ bias,
    float* __restrict__ out) {
  __shared__ unsigned short h_lds[1024];   // [r(16)][u(64)] bf16, XOR-swizzled
  __shared__ unsigned short e_lds[1024];
  const int tid = threadIdx.x, w = tid >> 6, ln = tid & 63;
  const int wg = blockIdx.x;               // rows wg*16 .. wg*16+15 ; bb == wg
  const int col = ln & 15, kq = ln >> 4;

  // ---- persistent B-fragments: W1 n-tiles {w,4+w,...,40+w}, Gz n-tiles {w,4+w,8+w} ----
  // q: 0=S 1=SPm 2=SPl 3=SEm 4=SEl 5..7=SGr(g) 8..10=SEG(g)
  bf16x8 BW1[11][2];
  {
    const int nts[11] = {w, 4 + w, 8 + w, 12 + w, 16 + w,
                         20 + w, 24 + w, 28 + w, 32 + w, 36 + w, 40 + w};
#pragma unroll
    for (int q = 0; q < 11; ++q)
#pragma unroll
      for (int ks = 0; ks < 2; ++ks) {
        bf16x8 v;
#pragma unroll
        for (int i = 0; i < 8; ++i) {
          int k = ks * 32 + kq * 8 + i;
          v[i] = (short)f2bf(W1[k * 704 + nts[q] * 16 + col]);
        }
        BW1[q][ks] = v;
      }
  }
  bf16x8 BGz[3][2];
#pragma unroll
  for (int g = 0; g < 3; ++g)
#pragma unroll
    for (int ks = 0; ks < 2; ++ks) {
      bf16x8 v;
#pragma unroll
      for (int i = 0; i < 8; ++i) {
        int k = ks * 32 + kq * 8 + i;
        v[i] = (short)f2bf(G[(128 + k) * 192 + g * 64 + w * 16 + col]);
      }
      BGz[g][ks] = v;
    }
  float b0g[3], b1g[3];
#pragma unroll
  for (int g = 0; g < 3; ++g) {
    b0g[g] = bias[g * 64 + w * 16 + col];
    b1g[g] = bias[192 + g * 64 + w * 16 + col];
  }
  // zero h
  for (int i = tid; i < 1024; i += 256) h_lds[i] = 0;

  // a prefetch (t=0): ct = {w, 4+w, 8+w, 12+w, 16+w} -> qmu, qlv, g2_z, g2_r, g2_h
  u16x4 aq[5];
  {
    const int cts[5] = {w, 4 + w, 8 + w, 12 + w, 16 + w};
#pragma unroll
    for (int p = 0; p < 5; ++p)
      aq[p] = *(const u16x4*)(afrag + ((((size_t)0 * 16 + wg) * 20 + cts[p]) * 64 + ln) * 4);
  }

  const size_t BTU = (size_t)NB * NT * NU;
  float* oz  = out;
  float* oqm = out + BTU;
  float* opm = out + 2 * BTU;
  float* oql = out + 3 * BTU;
  float* opl = out + 4 * BTU;

  const int abyte0 = (ln & 15) * 128 + kq * 16;       // A-frag base (h/e), + ks*64
  const int aswz = ((ln & 15) & 7) << 4;
  const f32x4 z4 = {0.f, 0.f, 0.f, 0.f};

  for (int t = 0; t < NT; ++t) {
    __syncthreads();                               // h ready (prev step / init)
    bf16x8 hA0 = *(const bf16x8*)((const char*)h_lds + (abyte0 ^ aswz));
    bf16x8 hA1 = *(const bf16x8*)((const char*)h_lds + ((abyte0 + 64) ^ aswz));

    f32x4 c1[11];
    // q_lv (q=4) first — it heads the serial chain; then q_mu; then the rest.
    c1[4] = mfma16(hA0, BW1[4][0], z4); c1[4] = mfma16(hA1, BW1[4][1], c1[4]);
    c1[3] = mfma16(hA0, BW1[3][0], z4); c1[3] = mfma16(hA1, BW1[3][1], c1[3]);
#pragma unroll
    for (int q = 0; q < 11; ++q)
      if (q != 3 && q != 4) {
        c1[q] = mfma16(hA0, BW1[q][0], z4); c1[q] = mfma16(hA1, BW1[q][1], c1[q]);
      }

    float qlv[4], ee[4];
#pragma unroll
    for (int j = 0; j < 4; ++j) {
      qlv[j] = bf2f((unsigned short)aq[1][j]) + c1[4][j];
      ee[j] = 0.5f * __expf(qlv[j]);
    }
#pragma unroll
    for (int j = 0; j < 4; ++j) {
      int r = kq * 4 + j;
      int byte = (r * 128 + (w * 16 + col) * 2) ^ ((r & 7) << 4);
      *(unsigned short*)((char*)e_lds + byte) = f2bf(ee[j]);
    }
    __syncthreads();                               // e ready
    bf16x8 eA0 = *(const bf16x8*)((const char*)e_lds + (abyte0 ^ aswz));
    bf16x8 eA1 = *(const bf16x8*)((const char*)e_lds + ((abyte0 + 64) ^ aswz));
    f32x4 c2[3];
#pragma unroll
    for (int g = 0; g < 3; ++g) {
      c2[g] = mfma16(eA0, BGz[g][0], z4); c2[g] = mfma16(eA1, BGz[g][1], c2[g]);
    }

    // gates + outputs
#pragma unroll
    for (int j = 0; j < 4; ++j) {
      int r = kq * 4 + j;
      float qmu = bf2f((unsigned short)aq[0][j]) + c1[3][j];
      float zz = qmu + ee[j];
      float hp = c1[0][j];
      float mx0 = bf2f((unsigned short)aq[2][j]) + b0g[0] + c1[8][j] + c2[0][j];
      float mx1 = bf2f((unsigned short)aq[3][j]) + b0g[1] + c1[9][j] + c2[1][j];
      float mx2 = bf2f((unsigned short)aq[4][j]) + b0g[2] + c1[10][j] + c2[2][j];
      float mh0 = b1g[0] + c1[5][j];
      float mh1 = b1g[1] + c1[6][j];
      float mh2 = b1g[2] + c1[7][j];
      float zt = 1.f / (1.f + __expf(-(mx0 + mh0)));
      float rt = 1.f / (1.f + __expf(-(mx1 + mh1)));
      float e2 = __expf(2.f * (mx2 + rt * mh2));
      float th = 1.f - 2.f / (e2 + 1.f);
      float hn = zt * hp + (1.f - zt) * th;
      int byte = (r * 128 + (w * 16 + col) * 2) ^ ((r & 7) << 4);
      *(unsigned short*)((char*)h_lds + byte) = f2bf(hn);
      size_t ob = ((size_t)(wg * 16 + r) * NT + t) * NU + w * 16 + col;
      oz[ob] = zz; oqm[ob] = qmu; opm[ob] = c1[1][j]; oql[ob] = qlv[j]; opl[ob] = c1[2][j];
    }
    // prefetch a for t+1 (full-step latency to cover)
    if (t + 1 < NT) {
      const int cts[5] = {w, 4 + w, 8 + w, 12 + w, 16 + w};
#pragma unroll
      for (int p = 0; p < 5; ++p)
        aq[p] = *(const u16x4*)(afrag + ((((size_t)(t + 1) * 16 + wg) * 20 + cts[p]) * 64 + ln) * 4);
    }
  }
}

extern "C" void kernel_launch(void* const* d_in, const int* in_sizes, int n_in,
                              void* d_out, int out_size, void* d_ws, size_t ws_size,
                              hipStream_t stream) {
  (void)in_sizes; (void)n_in; (void)out_size; (void)ws_size;
  const float* x   = (const float*)d_in[0];
  const float* Win = (const float*)d_in[1];
  const float* S   = (const float*)d_in[2];
  const float* Emu = (const float*)d_in[3];
  const float* Elv = (const float*)d_in[4];
  const float* Pm  = (const float*)d_in[5];
  const float* Pl  = (const float*)d_in[6];
  const float* G   = (const float*)d_in[7];
  const float* Gr  = (const float*)d_in[8];
  const float* bias= (const float*)d_in[9];
  float* out = (float*)d_out;

  float* wsf = (float*)d_ws;
  float* W1 = wsf;                        // 45056 f
  float* WX = wsf + 45056;                // 40960 f
  float* tmpGx = wsf + 86016;             // 24576 f
  unsigned short* WXfrag = (unsigned short*)(wsf + 110592);        // 40960 u16
  unsigned short* afrag = (unsigned short*)((char*)d_ws + (1u << 20)); // 160 MB

  static bool attr_set = false;
  if (!attr_set) {
    (void)hipFuncSetAttribute((const void*)k_proj,
                              hipFuncAttributeMaxDynamicSharedMemorySize, 114688);
    attr_set = true;
  }

  hipLaunchKernelGGL(k_fold1, dim3(288), dim3(256), 0, stream,
                     Win, S, Emu, Elv, Pm, Pl, G, Gr, W1, WX, tmpGx);
  hipLaunchKernelGGL(k_fold2, dim3(144), dim3(256), 0, stream, G, W1, WX, tmpGx);
  hipLaunchKernelGGL(k_fold3, dim3(160), dim3(256), 0, stream, WX, WXfrag);
  hipLaunchKernelGGL(k_proj, dim3(2048), dim3(512), 114688, stream, x, WXfrag, afrag);
  hipLaunchKernelGGL(k_scan, dim3(16), dim3(256), 0, stream, W1, afrag, G, bias, out);
}

// Round 3
// 1807.791 us; speedup vs baseline: 1.2550x; 1.2550x over previous
//
#include <hip/hip_runtime.h>
#include <hip/hip_bf16.h>
#include <stdint.h>

// Problem constants (fixed by reference)
#define NB 256      // batch
#define NT 1024     // timesteps
#define NF 128      // features
#define NU 64       // units

typedef __attribute__((ext_vector_type(8))) short bf16x8;
typedef __attribute__((ext_vector_type(4))) float f32x4;
typedef __attribute__((ext_vector_type(4))) unsigned short u16x4;

static __device__ __forceinline__ unsigned short f2bf(float f) {
  unsigned int u = __builtin_bit_cast(unsigned int, f);
  unsigned int r = (u + 0x7fffu + ((u >> 16) & 1u)) >> 16;   // RNE
  return (unsigned short)r;
}
static __device__ __forceinline__ float bf2f(unsigned short h) {
  unsigned int u = ((unsigned int)h) << 16;
  return __builtin_bit_cast(float, u);
}
static __device__ __forceinline__ f32x4 mfma16(bf16x8 a, bf16x8 b, f32x4 c) {
  return __builtin_amdgcn_mfma_f32_16x16x32_bf16(a, b, c, 0, 0, 0);
}

// Light barrier: waits ONLY on LDS ops (h/e hand-off), leaves global loads/stores
// in flight across the barrier (avoids the compiler's vmcnt(0) drain that made
// round-1's k_scan 4300 cy/step). Pattern per the verified 8-phase template.
static __device__ __forceinline__ void lds_barrier() {
  asm volatile("s_waitcnt lgkmcnt(0)" ::: "memory");
  __builtin_amdgcn_s_barrier();
  __builtin_amdgcn_sched_barrier(0);
}

// ---------------- ws layout (float units unless noted) ----------------
// W1   : 64 x 704 fp32 at [0, 45056)          cols: S|SPm|SPl|SEm|SEl|SGr(192)|SEG(192)
// WX   : 128 x 320 fp32 at [45056, 86016)     cols: Wqmu|Wqlv|Wg2(192)
// tmpGx: 128 x 192 fp32 at [86016, 110592)
// WXfrag: 40960 bf16 (u16) at float-offset 110592
// afrag : [t][bb(16)][ct(20)][lane(64)][j(4)] bf16 at byte offset 1<<20 (160 MB)

// =============== fold 1: first-level weight products ===============
__global__ __launch_bounds__(256) void k_fold1(
    const float* __restrict__ Win, const float* __restrict__ S,
    const float* __restrict__ Emu, const float* __restrict__ Elv,
    const float* __restrict__ Pm, const float* __restrict__ Pl,
    const float* __restrict__ G, const float* __restrict__ Gr,
    float* __restrict__ W1, float* __restrict__ WX, float* __restrict__ tmpGx) {
  int id = blockIdx.x * 256 + threadIdx.x;
  if (id < 8192) {                       // Wqmu = Win @ Emu[:128]
    int f = id >> 6, u = id & 63;
    float s = 0.f;
    for (int k = 0; k < 128; ++k) s += Win[f * 128 + k] * Emu[k * 64 + u];
    WX[f * 320 + u] = s;
  } else if (id < 16384) {               // Wqlv = Win @ Elv[:128]
    int r = id - 8192; int f = r >> 6, u = r & 63;
    float s = 0.f;
    for (int k = 0; k < 128; ++k) s += Win[f * 128 + k] * Elv[k * 64 + u];
    WX[f * 320 + 64 + u] = s;
  } else if (id < 40960) {               // tmpGx = Win @ G[:128]
    int r = id - 16384; int f = r / 192, n = r % 192;
    float s = 0.f;
    for (int k = 0; k < 128; ++k) s += Win[f * 128 + k] * G[k * 192 + n];
    tmpGx[f * 192 + n] = s;
  } else if (id < 45056) {               // S copy
    int r = id - 40960; int i = r >> 6, u = r & 63;
    W1[i * 704 + u] = S[i * 64 + u];
  } else if (id < 49152) {               // SPm = S @ Pm
    int r = id - 45056; int i = r >> 6, u = r & 63;
    float s = 0.f;
    for (int k = 0; k < 64; ++k) s += S[i * 64 + k] * Pm[k * 64 + u];
    W1[i * 704 + 64 + u] = s;
  } else if (id < 53248) {               // SPl = S @ Pl
    int r = id - 49152; int i = r >> 6, u = r & 63;
    float s = 0.f;
    for (int k = 0; k < 64; ++k) s += S[i * 64 + k] * Pl[k * 64 + u];
    W1[i * 704 + 128 + u] = s;
  } else if (id < 57344) {               // SEm = S @ Emu[128:]
    int r = id - 53248; int i = r >> 6, u = r & 63;
    float s = 0.f;
    for (int k = 0; k < 64; ++k) s += S[i * 64 + k] * Emu[(128 + k) * 64 + u];
    W1[i * 704 + 192 + u] = s;
  } else if (id < 61440) {               // SEl = S @ Elv[128:]
    int r = id - 57344; int i = r >> 6, u = r & 63;
    float s = 0.f;
    for (int k = 0; k < 64; ++k) s += S[i * 64 + k] * Elv[(128 + k) * 64 + u];
    W1[i * 704 + 256 + u] = s;
  } else if (id < 73728) {               // SGr = S @ Gr
    int r = id - 61440; int i = r / 192, n = r % 192;
    float s = 0.f;
    for (int k = 0; k < 64; ++k) s += S[i * 64 + k] * Gr[k * 192 + n];
    W1[i * 704 + 320 + n] = s;
  }
}

// =============== fold 2: second-level products (need fold1) ===============
__global__ __launch_bounds__(256) void k_fold2(
    const float* __restrict__ G, float* __restrict__ W1,
    float* __restrict__ WX, const float* __restrict__ tmpGx) {
  int id = blockIdx.x * 256 + threadIdx.x;
  if (id < 24576) {                      // Wg2 = tmpGx + Wqmu @ Gz
    int f = id / 192, n = id % 192;
    float s = tmpGx[f * 192 + n];
    for (int u = 0; u < 64; ++u) s += WX[f * 320 + u] * G[(128 + u) * 192 + n];
    WX[f * 320 + 128 + n] = s;
  } else if (id < 36864) {               // SEG = SEm @ Gz
    int r = id - 24576; int i = r / 192, n = r % 192;
    float s = 0.f;
    for (int u = 0; u < 64; ++u) s += W1[i * 704 + 192 + u] * G[(128 + u) * 192 + n];
    W1[i * 704 + 512 + n] = s;
  }
}

// =============== fold 3: pack WX into MFMA B-fragment order (bf16) ===============
__global__ __launch_bounds__(256) void k_fold3(
    const float* __restrict__ WX, unsigned short* __restrict__ WXfrag) {
  int d = blockIdx.x * 256 + threadIdx.x;   // 40960 elements
  if (d < 40960) {
    int i = d & 7, lane = (d >> 3) & 63, ks = (d >> 9) & 3, ct = d >> 11;
    int k = ks * 32 + (lane >> 4) * 8 + i;
    int n = ct * 16 + (lane & 15);
    WXfrag[d] = f2bf(WX[k * 320 + n]);
  }
}

// =============== projection GEMM: a = x @ WX, output in consumer-fragment order ===============
// grid 2048: wg -> t = wg>>1, b0 = (wg&1)*128. 512 threads = 8 waves.
__global__ __launch_bounds__(512, 1) void k_proj(
    const float* __restrict__ x, const unsigned short* __restrict__ WXfrag,
    unsigned short* __restrict__ afrag) {
  extern __shared__ char smem[];
  unsigned short* A  = (unsigned short*)smem;          // 128x128 bf16, XOR-swizzled (32 KB)
  unsigned short* Bf = (unsigned short*)(smem + 32768);// fragment-packed WX (80 KB)
  const int wgid = blockIdx.x;
  const int t = wgid >> 1, b0 = (wgid & 1) << 7;
  const int tid = threadIdx.x;

  // --- B staging: linear 80 KB copy (global -> LDS) ---
  {
    const f32x4* src = (const f32x4*)WXfrag;  // 5120 x 16B
    f32x4* dst = (f32x4*)Bf;
#pragma unroll
    for (int j = 0; j < 10; ++j) {
      int o = tid + j * 512;
      dst[o] = src[o];
    }
  }
  // --- A staging: x rows (b0..b0+127) at fixed t, cvt fp32->bf16, swizzled ---
  {
    int row = tid >> 2, fq = tid & 3;
    const float* xs = x + ((size_t)(b0 + row) * NT + t) * NF + fq * 32;
#pragma unroll
    for (int i = 0; i < 4; ++i) {
      f32x4 v0 = *(const f32x4*)(xs + i * 8);
      f32x4 v1 = *(const f32x4*)(xs + i * 8 + 4);
      bf16x8 p;
#pragma unroll
      for (int e = 0; e < 4; ++e) { p[e] = (short)f2bf(v0[e]); p[4 + e] = (short)f2bf(v1[e]); }
      int byte = (row * 256 + fq * 64 + i * 16) ^ ((row & 7) << 4);
      *(bf16x8*)((char*)A + byte) = p;
    }
  }
  __syncthreads();

  const int wv = tid >> 6, ln = tid & 63;
  const int mh = wv >> 2, ng = wv & 3;      // m-half (64 rows), n-group (5 ct)
  const int m15 = ln & 15, kq = ln >> 4;

  bf16x8 af[4][4];
#pragma unroll
  for (int mt = 0; mt < 4; ++mt) {
    int row = mh * 64 + mt * 16 + m15;
#pragma unroll
    for (int ks = 0; ks < 4; ++ks) {
      int byte = (row * 256 + ks * 64 + kq * 16) ^ ((row & 7) << 4);
      af[mt][ks] = *(const bf16x8*)((const char*)A + byte);
    }
  }
  f32x4 acc[5][4];
#pragma unroll
  for (int c5 = 0; c5 < 5; ++c5)
#pragma unroll
    for (int mt = 0; mt < 4; ++mt) acc[c5][mt] = (f32x4){0.f, 0.f, 0.f, 0.f};

#pragma unroll
  for (int c5 = 0; c5 < 5; ++c5) {
    int ct = ng * 5 + c5;
    bf16x8 bfr[4];
#pragma unroll
    for (int ks = 0; ks < 4; ++ks)
      bfr[ks] = *(const bf16x8*)((const char*)Bf + ((size_t)((ct * 4 + ks) * 64 + ln)) * 16);
#pragma unroll
    for (int mt = 0; mt < 4; ++mt)
#pragma unroll
      for (int ks = 0; ks < 4; ++ks)
        acc[c5][mt] = mfma16(af[mt][ks], bfr[ks], acc[c5][mt]);
  }
  // --- epilogue: store in consumer-fragment order, 8B per lane ---
#pragma unroll
  for (int c5 = 0; c5 < 5; ++c5) {
    int ct = ng * 5 + c5;
#pragma unroll
    for (int mt = 0; mt < 4; ++mt) {
      int bb = (b0 >> 4) + mh * 4 + mt;
      size_t idx = (((size_t)t * 16 + bb) * 20 + ct) * 64 + ln;
      u16x4 pk;
#pragma unroll
      for (int j = 0; j < 4; ++j) pk[j] = f2bf(acc[c5][mt][j]);
      *(u16x4*)(afrag + idx * 4) = pk;
    }
  }
}

// =============== the scan: 16 wgs x 16 rows, 4 waves, weights in registers ===============
__global__ __launch_bounds__(256, 1) void k_scan(
    const float* __restrict__ W1, const unsigned short* __restrict__ afrag,
    const float* __restrict__ G, const float* __restrict__ bias,
    float* __restrict__ out) {
  __shared__ unsigned short h_lds[1024];   // [r(16)][u(64)] bf16, XOR-swizzled
  __shared__ unsigned short e_lds[1024];
  const int tid = threadIdx.x, w = tid >> 6, ln = tid & 63;
  const int wg = blockIdx.x;               // rows wg*16 .. wg*16+15 ; bb == wg
  const int col = ln & 15, kq = ln >> 4;

  // ---- persistent B-fragments: W1 n-tiles {w,4+w,...,40+w}, Gz n-tiles {w,4+w,8+w} ----
  // q: 0=S 1=SPm 2=SPl 3=SEm 4=SEl 5..7=SGr(g) 8..10=SEG(g)
  bf16x8 BW1[11][2];
  {
    const int nts[11] = {w, 4 + w, 8 + w, 12 + w, 16 + w,
                         20 + w, 24 + w, 28 + w, 32 + w, 36 + w, 40 + w};
#pragma unroll
    for (int q = 0; q < 11; ++q)
#pragma unroll
      for (int ks = 0; ks < 2; ++ks) {
        bf16x8 v;
#pragma unroll
        for (int i = 0; i < 8; ++i) {
          int k = ks * 32 + kq * 8 + i;
          v[i] = (short)f2bf(W1[k * 704 + nts[q] * 16 + col]);
        }
        BW1[q][ks] = v;
      }
  }
  bf16x8 BGz[3][2];
#pragma unroll
  for (int g = 0; g < 3; ++g)
#pragma unroll
    for (int ks = 0; ks < 2; ++ks) {
      bf16x8 v;
#pragma unroll
      for (int i = 0; i < 8; ++i) {
        int k = ks * 32 + kq * 8 + i;
        v[i] = (short)f2bf(G[(128 + k) * 192 + g * 64 + w * 16 + col]);
      }
      BGz[g][ks] = v;
    }
  float b0g[3], b1g[3];
#pragma unroll
  for (int g = 0; g < 3; ++g) {
    b0g[g] = bias[g * 64 + w * 16 + col];
    b1g[g] = bias[192 + g * 64 + w * 16 + col];
  }
  // zero h
  for (int i = tid; i < 1024; i += 256) h_lds[i] = 0;

  const int cts[5] = {w, 4 + w, 8 + w, 12 + w, 16 + w};
  // a prefetch (t=0) into buffer A
  u16x4 aqA[5], aqB[5];
#pragma unroll
  for (int p = 0; p < 5; ++p)
    aqA[p] = *(const u16x4*)(afrag + ((((size_t)0 * 16 + wg) * 20 + cts[p]) * 64 + ln) * 4);

  const size_t BTU = (size_t)NB * NT * NU;
  float* oz  = out;
  float* oqm = out + BTU;
  float* opm = out + 2 * BTU;
  float* oql = out + 3 * BTU;
  float* opl = out + 4 * BTU;

  const int abyte0 = (ln & 15) * 128 + kq * 16;       // A-frag base (h/e), + ks*64
  const int aswz = ((ln & 15) & 7) << 4;
  const f32x4 z4 = {0.f, 0.f, 0.f, 0.f};

  // One scan step. AQC = this step's x-projection fragments; AQN gets t+1's
  // (issued right after the h-barrier so HBM/L3 latency hides under the step).
  auto step = [&](const u16x4 (&AQC)[5], u16x4 (&AQN)[5], int t) {
    lds_barrier();                                 // h ready (prev step / init)
    {
      int tn = (t + 1 < NT) ? (t + 1) : (NT - 1);
#pragma unroll
      for (int p = 0; p < 5; ++p)
        AQN[p] = *(const u16x4*)(afrag + ((((size_t)tn * 16 + wg) * 20 + cts[p]) * 64 + ln) * 4);
    }
    bf16x8 hA0 = *(const bf16x8*)((const char*)h_lds + (abyte0 ^ aswz));
    bf16x8 hA1 = *(const bf16x8*)((const char*)h_lds + ((abyte0 + 64) ^ aswz));

    f32x4 c1[11];
    // q_lv (q=4) first — it heads the serial chain; then q_mu; then the rest.
    c1[4] = mfma16(hA0, BW1[4][0], z4); c1[4] = mfma16(hA1, BW1[4][1], c1[4]);
    c1[3] = mfma16(hA0, BW1[3][0], z4); c1[3] = mfma16(hA1, BW1[3][1], c1[3]);
#pragma unroll
    for (int q = 0; q < 11; ++q)
      if (q != 3 && q != 4) {
        c1[q] = mfma16(hA0, BW1[q][0], z4); c1[q] = mfma16(hA1, BW1[q][1], c1[q]);
      }

    float qlv[4], ee[4];
#pragma unroll
    for (int j = 0; j < 4; ++j) {
      qlv[j] = bf2f((unsigned short)AQC[1][j]) + c1[4][j];
      ee[j] = 0.5f * __expf(qlv[j]);
    }
#pragma unroll
    for (int j = 0; j < 4; ++j) {
      int r = kq * 4 + j;
      int byte = (r * 128 + (w * 16 + col) * 2) ^ ((r & 7) << 4);
      *(unsigned short*)((char*)e_lds + byte) = f2bf(ee[j]);
    }
    lds_barrier();                                 // e ready
    bf16x8 eA0 = *(const bf16x8*)((const char*)e_lds + (abyte0 ^ aswz));
    bf16x8 eA1 = *(const bf16x8*)((const char*)e_lds + ((abyte0 + 64) ^ aswz));
    f32x4 c2[3];
#pragma unroll
    for (int g = 0; g < 3; ++g) {
      c2[g] = mfma16(eA0, BGz[g][0], z4); c2[g] = mfma16(eA1, BGz[g][1], c2[g]);
    }

    // gates: compute h_new and write LDS first (critical path), then stream outputs
    float qmu[4], hn[4], hp4[4];
#pragma unroll
    for (int j = 0; j < 4; ++j) {
      qmu[j] = bf2f((unsigned short)AQC[0][j]) + c1[3][j];
      float hp = c1[0][j];
      hp4[j] = hp;
      float mx0 = bf2f((unsigned short)AQC[2][j]) + b0g[0] + c1[8][j] + c2[0][j];
      float mx1 = bf2f((unsigned short)AQC[3][j]) + b0g[1] + c1[9][j] + c2[1][j];
      float mx2 = bf2f((unsigned short)AQC[4][j]) + b0g[2] + c1[10][j] + c2[2][j];
      float mh0 = b1g[0] + c1[5][j];
      float mh1 = b1g[1] + c1[6][j];
      float mh2 = b1g[2] + c1[7][j];
      float zt = 1.f / (1.f + __expf(-(mx0 + mh0)));
      float rt = 1.f / (1.f + __expf(-(mx1 + mh1)));
      float e2 = __expf(2.f * (mx2 + rt * mh2));
      float th = 1.f - 2.f / (e2 + 1.f);
      hn[j] = zt * hp + (1.f - zt) * th;
      int r = kq * 4 + j;
      int byte = (r * 128 + (w * 16 + col) * 2) ^ ((r & 7) << 4);
      *(unsigned short*)((char*)h_lds + byte) = f2bf(hn[j]);
    }
#pragma unroll
    for (int j = 0; j < 4; ++j) {
      int r = kq * 4 + j;
      size_t ob = ((size_t)(wg * 16 + r) * NT + t) * NU + w * 16 + col;
      oz[ob] = qmu[j] + ee[j]; oqm[ob] = qmu[j]; opm[ob] = c1[1][j];
      oql[ob] = qlv[j]; opl[ob] = c1[2][j];
    }
  };

  for (int t = 0; t < NT; t += 2) {
    step(aqA, aqB, t);
    step(aqB, aqA, t + 1);
  }
}

extern "C" void kernel_launch(void* const* d_in, const int* in_sizes, int n_in,
                              void* d_out, int out_size, void* d_ws, size_t ws_size,
                              hipStream_t stream) {
  (void)in_sizes; (void)n_in; (void)out_size; (void)ws_size;
  const float* x   = (const float*)d_in[0];
  const float* Win = (const float*)d_in[1];
  const float* S   = (const float*)d_in[2];
  const float* Emu = (const float*)d_in[3];
  const float* Elv = (const float*)d_in[4];
  const float* Pm  = (const float*)d_in[5];
  const float* Pl  = (const float*)d_in[6];
  const float* G   = (const float*)d_in[7];
  const float* Gr  = (const float*)d_in[8];
  const float* bias= (const float*)d_in[9];
  float* out = (float*)d_out;

  float* wsf = (float*)d_ws;
  float* W1 = wsf;                        // 45056 f
  float* WX = wsf + 45056;                // 40960 f
  float* tmpGx = wsf + 86016;             // 24576 f
  unsigned short* WXfrag = (unsigned short*)(wsf + 110592);        // 40960 u16
  unsigned short* afrag = (unsigned short*)((char*)d_ws + (1u << 20)); // 160 MB

  (void)hipFuncSetAttribute((const void*)k_proj,
                            hipFuncAttributeMaxDynamicSharedMemorySize, 114688);

  hipLaunchKernelGGL(k_fold1, dim3(288), dim3(256), 0, stream,
                     Win, S, Emu, Elv, Pm, Pl, G, Gr, W1, WX, tmpGx);
  hipLaunchKernelGGL(k_fold2, dim3(144), dim3(256), 0, stream, G, W1, WX, tmpGx);
  hipLaunchKernelGGL(k_fold3, dim3(160), dim3(256), 0, stream, WX, WXfrag);
  hipLaunchKernelGGL(k_proj, dim3(2048), dim3(512), 114688, stream, x, WXfrag, afrag);
  hipLaunchKernelGGL(k_scan, dim3(16), dim3(256), 0, stream, W1, afrag, G, bias, out);
}